// Round 1
// baseline (674.822 us; speedup 1.0000x reference)
//
#include <hip/hip_runtime.h>
#include <hip/hip_bf16.h>
#include <math.h>

#define TPB 256

static __device__ __forceinline__ float bf2f(unsigned int u) {
  union { unsigned int i; float f; } c; c.i = u << 16; return c.f;
}
static __device__ __forceinline__ unsigned short f2bf(float f) {
  union { float f; unsigned int i; } c; c.f = f;
  unsigned int lsb = (c.i >> 16) & 1u;
  return (unsigned short)((c.i + 0x7fffu + lsb) >> 16);
}
static __device__ __forceinline__ float lrelu(float v) {
  return v > 0.f ? v : 0.2f * v;
}

// ---------------- CSR build ----------------
__global__ void k_deg(const int* __restrict__ ei, int E, int ET, int* __restrict__ deg) {
  int e = blockIdx.x * blockDim.x + threadIdx.x;
  if (e >= ET) return;
  int dst = (e < E) ? ei[E + e] : (e - E);
  atomicAdd(&deg[dst], 1);
}

__global__ void k_scan1(const int* __restrict__ deg, int N, int* __restrict__ bsum) {
  __shared__ int sm[TPB];
  int i = blockIdx.x * TPB + threadIdx.x;
  sm[threadIdx.x] = (i < N) ? deg[i] : 0;
  __syncthreads();
  for (int d = TPB / 2; d > 0; d >>= 1) {
    if (threadIdx.x < d) sm[threadIdx.x] += sm[threadIdx.x + d];
    __syncthreads();
  }
  if (threadIdx.x == 0) bsum[blockIdx.x] = sm[0];
}

__global__ void k_scan2(const int* __restrict__ bsum, int SB, int* __restrict__ bpre,
                        int* __restrict__ rowoff, int N) {
  if (threadIdx.x == 0 && blockIdx.x == 0) {
    int run = 0;
    for (int b = 0; b < SB; ++b) { bpre[b] = run; run += bsum[b]; }
    rowoff[N] = run;
  }
}

__global__ void k_scan3(const int* __restrict__ deg, const int* __restrict__ bpre,
                        int N, int* __restrict__ rowoff, int* __restrict__ cursor) {
  __shared__ int sm[TPB];
  int i = blockIdx.x * TPB + threadIdx.x;
  int v = (i < N) ? deg[i] : 0;
  sm[threadIdx.x] = v;
  __syncthreads();
  for (int d = 1; d < TPB; d <<= 1) {
    int t = (threadIdx.x >= d) ? sm[threadIdx.x - d] : 0;
    __syncthreads();
    sm[threadIdx.x] += t;
    __syncthreads();
  }
  if (i < N) {
    int off = bpre[blockIdx.x] + sm[threadIdx.x] - v;  // exclusive
    rowoff[i] = off;
    cursor[i] = off;
  }
}

__global__ void k_fill(const int* __restrict__ ei, int E, int ET,
                       int* __restrict__ cursor, int* __restrict__ csrc) {
  int e = blockIdx.x * blockDim.x + threadIdx.x;
  if (e >= ET) return;
  int src, dst;
  if (e < E) { src = ei[e]; dst = ei[E + e]; } else { src = dst = e - E; }
  int pos = atomicAdd(&cursor[dst], 1);
  csrc[pos] = src;
}

// ---------------- GEMM: out_bf16 = A[M,K] @ W[K,Nc] + bias ----------------
__global__ void k_gemm(const float* __restrict__ A, const float* __restrict__ W,
                       const float* __restrict__ bias, unsigned short* __restrict__ out,
                       int M, int K, int Nc) {
  __shared__ float As[128 * 68];  // transposed: As[k*68 + row]
  __shared__ float Bs[128 * 64];  // Bs[k*64 + col]
  int r0 = blockIdx.x * 64, n0 = blockIdx.y * 64;
  int tid = threadIdx.x;
  int kq = K >> 2;
  for (int idx = tid; idx < 16 * K; idx += TPB) {
    int row = idx / kq; int k4 = (idx - row * kq) * 4;
    float4 v = make_float4(0.f, 0.f, 0.f, 0.f);
    int gr = r0 + row;
    if (gr < M) v = *(const float4*)(A + (size_t)gr * K + k4);
    As[(k4 + 0) * 68 + row] = v.x;
    As[(k4 + 1) * 68 + row] = v.y;
    As[(k4 + 2) * 68 + row] = v.z;
    As[(k4 + 3) * 68 + row] = v.w;
  }
  for (int idx = tid; idx < 16 * K; idx += TPB) {
    int k = idx >> 4; int c4 = (idx & 15) * 4;
    *(float4*)(&Bs[k * 64 + c4]) = *(const float4*)(W + (size_t)k * Nc + n0 + c4);
  }
  __syncthreads();
  int tx = tid & 15, ty = tid >> 4;
  float acc[4][4];
#pragma unroll
  for (int i = 0; i < 4; ++i)
#pragma unroll
    for (int j = 0; j < 4; ++j) acc[i][j] = 0.f;
  for (int k = 0; k < K; ++k) {
    float4 a4 = *(const float4*)(&As[k * 68 + ty * 4]);
    float4 b4 = *(const float4*)(&Bs[k * 64 + tx * 4]);
    float av[4] = {a4.x, a4.y, a4.z, a4.w};
    float bv[4] = {b4.x, b4.y, b4.z, b4.w};
#pragma unroll
    for (int i = 0; i < 4; ++i)
#pragma unroll
      for (int j = 0; j < 4; ++j) acc[i][j] += av[i] * bv[j];
  }
  float4 bb = *(const float4*)(bias + n0 + tx * 4);
  float bvb[4] = {bb.x, bb.y, bb.z, bb.w};
#pragma unroll
  for (int i = 0; i < 4; ++i) {
    int gr = r0 + ty * 4 + i;
    if (gr < M) {
      ushort4 o;
      o.x = f2bf(acc[i][0] + bvb[0]);
      o.y = f2bf(acc[i][1] + bvb[1]);
      o.z = f2bf(acc[i][2] + bvb[2]);
      o.w = f2bf(acc[i][3] + bvb[3]);
      *(ushort4*)(out + (size_t)gr * Nc + n0 + tx * 4) = o;
    }
  }
}

// ---------------- Fused GATv2 layer 1: H=4, C=64, mean over heads + bias ----------------
__global__ void k_gat1(const unsigned short* __restrict__ xl,
                       const unsigned short* __restrict__ xr,
                       const int* __restrict__ rowoff, const int* __restrict__ csrc,
                       const float* __restrict__ att, const float* __restrict__ bias,
                       float* __restrict__ out, int N) {
  int node = (blockIdx.x * blockDim.x + threadIdx.x) >> 6;
  int lane = threadIdx.x & 63;
  if (node >= N) return;
  int l4 = lane * 4;
  uint2 rv = *(const uint2*)(xr + (size_t)node * 256 + l4);
  float xr0 = bf2f(rv.x & 0xffffu), xr1 = bf2f(rv.x >> 16);
  float xr2 = bf2f(rv.y & 0xffffu), xr3 = bf2f(rv.y >> 16);
  float4 at = *(const float4*)(att + l4);
  int beg = rowoff[node], end = rowoff[node + 1];
  float m = -INFINITY, s = 0.f;
  float a0 = 0.f, a1 = 0.f, a2 = 0.f, a3 = 0.f;
  for (int k = beg; k < end; ++k) {
    int src = csrc[k];
    uint2 v = *(const uint2*)(xl + (size_t)src * 256 + l4);
    float x0 = bf2f(v.x & 0xffffu), x1 = bf2f(v.x >> 16);
    float x2 = bf2f(v.y & 0xffffu), x3 = bf2f(v.y >> 16);
    float p = lrelu(x0 + xr0) * at.x + lrelu(x1 + xr1) * at.y
            + lrelu(x2 + xr2) * at.z + lrelu(x3 + xr3) * at.w;
    // reduce logit within 16-lane head group
    p += __shfl_xor(p, 1); p += __shfl_xor(p, 2);
    p += __shfl_xor(p, 4); p += __shfl_xor(p, 8);
    float mn = fmaxf(m, p);
    float sc = __expf(m - mn);
    float w = __expf(p - mn);
    s = s * sc + w;
    a0 = a0 * sc + w * x0;
    a1 = a1 * sc + w * x1;
    a2 = a2 * sc + w * x2;
    a3 = a3 * sc + w * x3;
    m = mn;
  }
  float inv = 1.f / (s + 1e-16f);
  a0 *= inv; a1 *= inv; a2 *= inv; a3 *= inv;
  // sum over the 4 heads (xor lanes 16, 32)
  a0 += __shfl_xor(a0, 16); a0 += __shfl_xor(a0, 32);
  a1 += __shfl_xor(a1, 16); a1 += __shfl_xor(a1, 32);
  a2 += __shfl_xor(a2, 16); a2 += __shfl_xor(a2, 32);
  a3 += __shfl_xor(a3, 16); a3 += __shfl_xor(a3, 32);
  if (lane < 16) {
    float4 o;
    o.x = a0 * 0.25f + bias[l4 + 0];
    o.y = a1 * 0.25f + bias[l4 + 1];
    o.z = a2 * 0.25f + bias[l4 + 2];
    o.w = a3 * 0.25f + bias[l4 + 3];
    *(float4*)(out + (size_t)node * 64 + l4) = o;
  }
}

// ---------------- Fused GATv2 layer 2: H=1, C=64 ----------------
__global__ void k_gat2(const unsigned short* __restrict__ xl,
                       const unsigned short* __restrict__ xr,
                       const int* __restrict__ rowoff, const int* __restrict__ csrc,
                       const float* __restrict__ att, const float* __restrict__ bias,
                       float* __restrict__ out, int N) {
  int node = (blockIdx.x * blockDim.x + threadIdx.x) >> 6;
  int lane = threadIdx.x & 63;
  if (node >= N) return;
  float xrc = bf2f(xr[(size_t)node * 64 + lane]);
  float ac = att[lane];
  int beg = rowoff[node], end = rowoff[node + 1];
  float m = -INFINITY, s = 0.f, acc = 0.f;
  for (int k = beg; k < end; ++k) {
    int src = csrc[k];
    float x = bf2f(xl[(size_t)src * 64 + lane]);
    float p = lrelu(x + xrc) * ac;
    p += __shfl_xor(p, 1); p += __shfl_xor(p, 2); p += __shfl_xor(p, 4);
    p += __shfl_xor(p, 8); p += __shfl_xor(p, 16); p += __shfl_xor(p, 32);
    float mn = fmaxf(m, p);
    float sc = __expf(m - mn);
    float w = __expf(p - mn);
    s = s * sc + w;
    acc = acc * sc + w * x;
    m = mn;
  }
  out[(size_t)node * 64 + lane] = acc / (s + 1e-16f) + bias[lane];
}

// ---------------- BatchNorm ----------------
__global__ void k_bnstat(const float* __restrict__ in, int N, float* __restrict__ part) {
  __shared__ float sm[TPB], sq[TPB];
  int col = threadIdx.x & 63;
  int rq = threadIdx.x >> 6;
  float s = 0.f, q = 0.f;
  for (int r = blockIdx.x * 4 + rq; r < N; r += gridDim.x * 4) {
    float v = in[(size_t)r * 64 + col];
    s += v; q += v * v;
  }
  sm[threadIdx.x] = s; sq[threadIdx.x] = q;
  __syncthreads();
  if (threadIdx.x < 64) {
    s = sm[threadIdx.x] + sm[threadIdx.x + 64] + sm[threadIdx.x + 128] + sm[threadIdx.x + 192];
    q = sq[threadIdx.x] + sq[threadIdx.x + 64] + sq[threadIdx.x + 128] + sq[threadIdx.x + 192];
    part[(size_t)blockIdx.x * 128 + threadIdx.x] = s;
    part[(size_t)blockIdx.x * 128 + 64 + threadIdx.x] = q;
  }
}

__global__ void k_bnfin(const float* __restrict__ part, int B, int N,
                        const float* __restrict__ g, const float* __restrict__ beta,
                        float* __restrict__ ab) {
  int c = threadIdx.x;  // 64 threads
  float s = 0.f, q = 0.f;
  for (int b = 0; b < B; ++b) {
    s += part[(size_t)b * 128 + c];
    q += part[(size_t)b * 128 + 64 + c];
  }
  float mean = s / (float)N;
  float var = q / (float)N - mean * mean;
  float a = g[c] * rsqrtf(var + 1e-5f);
  ab[c] = a;
  ab[64 + c] = beta[c] - mean * a;
}

__global__ void k_bnapply(const float* __restrict__ in, const float* __restrict__ ab,
                          float* __restrict__ out, int total4) {
  int idx = blockIdx.x * blockDim.x + threadIdx.x;
  if (idx >= total4) return;
  float4 v = *(const float4*)(in + (size_t)idx * 4);
  int c0 = (idx & 15) * 4;
  v.x = fmaxf(v.x * ab[c0 + 0] + ab[64 + c0 + 0], 0.f);
  v.y = fmaxf(v.y * ab[c0 + 1] + ab[64 + c0 + 1], 0.f);
  v.z = fmaxf(v.z * ab[c0 + 2] + ab[64 + c0 + 2], 0.f);
  v.w = fmaxf(v.w * ab[c0 + 3] + ab[64 + c0 + 3], 0.f);
  *(float4*)(out + (size_t)idx * 4) = v;
}

extern "C" void kernel_launch(void* const* d_in, const int* in_sizes, int n_in,
                              void* d_out, int out_size, void* d_ws, size_t ws_size,
                              hipStream_t stream) {
  const float* x     = (const float*)d_in[0];
  const int*   ei    = (const int*)d_in[1];
  const float* Wl1   = (const float*)d_in[2];
  const float* bl1   = (const float*)d_in[3];
  const float* Wr1   = (const float*)d_in[4];
  const float* br1   = (const float*)d_in[5];
  const float* att1  = (const float*)d_in[6];
  const float* bias1 = (const float*)d_in[7];
  const float* g1    = (const float*)d_in[8];
  const float* be1   = (const float*)d_in[9];
  const float* Wl2   = (const float*)d_in[10];
  const float* bl2   = (const float*)d_in[11];
  const float* Wr2   = (const float*)d_in[12];
  const float* br2   = (const float*)d_in[13];
  const float* att2  = (const float*)d_in[14];
  const float* bias2 = (const float*)d_in[15];
  const float* g2    = (const float*)d_in[16];
  const float* be2   = (const float*)d_in[17];
  float* out = (float*)d_out;

  const int N  = in_sizes[0] / 128;   // 50000
  const int E  = in_sizes[1] / 2;     // 800000
  const int ET = E + N;               // + self loops
  const int SB = (N + TPB - 1) / TPB;

  char* p = (char*)d_ws;
  auto take = [&](size_t b) { char* q = p; p += (b + 255) & ~(size_t)255; return q; };

  unsigned short* xl1 = (unsigned short*)take((size_t)N * 256 * 2);
  unsigned short* xr1 = (unsigned short*)take((size_t)N * 256 * 2);
  unsigned short* xl2 = (unsigned short*)take((size_t)N * 64 * 2);
  unsigned short* xr2 = (unsigned short*)take((size_t)N * 64 * 2);
  float* out1 = (float*)take((size_t)N * 64 * 4);
  float* h1   = (float*)take((size_t)N * 64 * 4);
  int* deg    = (int*)take((size_t)N * 4);
  int* rowoff = (int*)take((size_t)(N + 1) * 4);
  int* cursor = (int*)take((size_t)N * 4);
  int* csrc   = (int*)take((size_t)ET * 4);
  int* bsum   = (int*)take((size_t)SB * 4);
  int* bpre   = (int*)take((size_t)SB * 4);
  float* part = (float*)take((size_t)128 * 128 * 4);
  float* ab1  = (float*)take(128 * 4);
  float* ab2  = (float*)take(128 * 4);
  (void)ws_size; (void)n_in; (void)out_size;

  int egrid = (ET + TPB - 1) / TPB;
  int ngrid = (N + 3) / 4;           // 4 wave-nodes per block
  int mtile = (N + 63) / 64;
  int total4 = N * 16;               // N*64/4

  // CSR build
  hipMemsetAsync(deg, 0, (size_t)N * 4, stream);
  k_deg<<<egrid, TPB, 0, stream>>>(ei, E, ET, deg);
  k_scan1<<<SB, TPB, 0, stream>>>(deg, N, bsum);
  k_scan2<<<1, 64, 0, stream>>>(bsum, SB, bpre, rowoff, N);
  k_scan3<<<SB, TPB, 0, stream>>>(deg, bpre, N, rowoff, cursor);
  k_fill<<<egrid, TPB, 0, stream>>>(ei, E, ET, cursor, csrc);

  // Layer 1
  k_gemm<<<dim3(mtile, 4), TPB, 0, stream>>>(x, Wl1, bl1, xl1, N, 128, 256);
  k_gemm<<<dim3(mtile, 4), TPB, 0, stream>>>(x, Wr1, br1, xr1, N, 128, 256);
  k_gat1<<<ngrid, TPB, 0, stream>>>(xl1, xr1, rowoff, csrc, att1, bias1, out1, N);
  k_bnstat<<<128, TPB, 0, stream>>>(out1, N, part);
  k_bnfin<<<1, 64, 0, stream>>>(part, 128, N, g1, be1, ab1);
  k_bnapply<<<(total4 + TPB - 1) / TPB, TPB, 0, stream>>>(out1, ab1, h1, total4);

  // Layer 2
  k_gemm<<<dim3(mtile, 1), TPB, 0, stream>>>(h1, Wl2, bl2, xl2, N, 64, 64);
  k_gemm<<<dim3(mtile, 1), TPB, 0, stream>>>(h1, Wr2, br2, xr2, N, 64, 64);
  k_gat2<<<ngrid, TPB, 0, stream>>>(xl2, xr2, rowoff, csrc, att2, bias2, out, N);
  k_bnstat<<<128, TPB, 0, stream>>>(out, N, part);
  k_bnfin<<<1, 64, 0, stream>>>(part, 128, N, g2, be2, ab2);
  k_bnapply<<<(total4 + TPB - 1) / TPB, TPB, 0, stream>>>(out, ab2, out, total4);
}

// Round 2
// 406.867 us; speedup vs baseline: 1.6586x; 1.6586x over previous
//
#include <hip/hip_runtime.h>
#include <hip/hip_bf16.h>
#include <math.h>

#define TPB 256

typedef __attribute__((ext_vector_type(8))) short bfrag8;
typedef __attribute__((ext_vector_type(4))) float f32x4;

static __device__ __forceinline__ float bf2f(unsigned int u) {
  union { unsigned int i; float f; } c; c.i = u << 16; return c.f;
}
static __device__ __forceinline__ unsigned short f2bf(float f) {
  union { float f; unsigned int i; } c; c.f = f;
  unsigned int lsb = (c.i >> 16) & 1u;
  return (unsigned short)((c.i + 0x7fffu + lsb) >> 16);
}
static __device__ __forceinline__ float lrelu(float v) {
  return v > 0.f ? v : 0.2f * v;
}

// ---------------- CSR build ----------------
__global__ void k_deg(const int* __restrict__ ei, int E, int ET, int* __restrict__ deg) {
  int e = blockIdx.x * blockDim.x + threadIdx.x;
  if (e >= ET) return;
  int dst = (e < E) ? ei[E + e] : (e - E);
  atomicAdd(&deg[dst], 1);
}

__global__ void k_scan1(const int* __restrict__ deg, int N, int* __restrict__ bsum) {
  __shared__ int sm[TPB];
  int i = blockIdx.x * TPB + threadIdx.x;
  sm[threadIdx.x] = (i < N) ? deg[i] : 0;
  __syncthreads();
  for (int d = TPB / 2; d > 0; d >>= 1) {
    if (threadIdx.x < d) sm[threadIdx.x] += sm[threadIdx.x + d];
    __syncthreads();
  }
  if (threadIdx.x == 0) bsum[blockIdx.x] = sm[0];
}

// single block, SB <= TPB
__global__ void k_scan2(const int* __restrict__ bsum, int SB, int* __restrict__ bpre,
                        int* __restrict__ rowoff, int N) {
  __shared__ int sm[TPB];
  int v = (threadIdx.x < SB) ? bsum[threadIdx.x] : 0;
  sm[threadIdx.x] = v;
  __syncthreads();
  for (int d = 1; d < TPB; d <<= 1) {
    int t = (threadIdx.x >= d) ? sm[threadIdx.x - d] : 0;
    __syncthreads();
    sm[threadIdx.x] += t;
    __syncthreads();
  }
  if (threadIdx.x < SB) bpre[threadIdx.x] = sm[threadIdx.x] - v;
  if (threadIdx.x == SB - 1) rowoff[N] = sm[SB - 1];
}

__global__ void k_scan3(const int* __restrict__ deg, const int* __restrict__ bpre,
                        int N, int* __restrict__ rowoff, int* __restrict__ cursor) {
  __shared__ int sm[TPB];
  int i = blockIdx.x * TPB + threadIdx.x;
  int v = (i < N) ? deg[i] : 0;
  sm[threadIdx.x] = v;
  __syncthreads();
  for (int d = 1; d < TPB; d <<= 1) {
    int t = (threadIdx.x >= d) ? sm[threadIdx.x - d] : 0;
    __syncthreads();
    sm[threadIdx.x] += t;
    __syncthreads();
  }
  if (i < N) {
    int off = bpre[blockIdx.x] + sm[threadIdx.x] - v;  // exclusive
    rowoff[i] = off;
    cursor[i] = off;
  }
}

__global__ void k_fill(const int* __restrict__ ei, int E, int ET,
                       int* __restrict__ cursor, int* __restrict__ csrc) {
  int e = blockIdx.x * blockDim.x + threadIdx.x;
  if (e >= ET) return;
  int src, dst;
  if (e < E) { src = ei[e]; dst = ei[E + e]; } else { src = dst = e - E; }
  int pos = atomicAdd(&cursor[dst], 1);
  csrc[pos] = src;
}

// ---------------- Fused MFMA GEMM: out{0,1}_bf16 = act(A) @ W{0,1} + b{0,1} ----------------
// A [M,K] f32 (optional per-column affine+relu), W [K,Nc] f32, tile 64 rows x 64 cols.
// LDS: As[row][K] bf16, B*s[col][K] bf16 (transposed), all XOR-swizzled (G4/T2).
__global__ void k_gemm_mfma(const float* __restrict__ A,
                            const float* __restrict__ W0, const float* __restrict__ b0,
                            const float* __restrict__ W1, const float* __restrict__ b1,
                            unsigned short* __restrict__ out0, unsigned short* __restrict__ out1,
                            int M, int K, int Nc, const float* __restrict__ affine) {
  __shared__ short As[64 * 128];
  __shared__ short Bls[64 * 128];
  __shared__ short Brs[64 * 128];
  const int r0 = blockIdx.x * 64, n0 = blockIdx.y * 64;
  const int tid = threadIdx.x;
  const int Kb = K * 2;  // row byte stride

  // ---- stage A (f32 -> bf16, optional BN-affine+relu), swizzled ----
  const int kq = K >> 2;  // float4 per row
  for (int idx = tid; idx < 16 * K; idx += TPB) {
    int row = idx / kq, c4 = idx - row * kq;
    int gr = r0 + row;
    float4 v = make_float4(0.f, 0.f, 0.f, 0.f);
    if (gr < M) v = *(const float4*)(A + (size_t)gr * K + c4 * 4);
    if (affine) {
      int c = c4 * 4;
      v.x = fmaxf(v.x * affine[c + 0] + affine[64 + c + 0], 0.f);
      v.y = fmaxf(v.y * affine[c + 1] + affine[64 + c + 1], 0.f);
      v.z = fmaxf(v.z * affine[c + 2] + affine[64 + c + 2], 0.f);
      v.w = fmaxf(v.w * affine[c + 3] + affine[64 + c + 3], 0.f);
    }
    ushort4 pk; pk.x = f2bf(v.x); pk.y = f2bf(v.y); pk.z = f2bf(v.z); pk.w = f2bf(v.w);
    int kb = (c4 * 8) ^ ((row & 7) << 4);
    *(ushort4*)((char*)As + row * Kb + kb) = pk;
  }
  // ---- stage W0/W1 transposed: B[col][k], swizzled ----
  for (int idx = tid; idx < 16 * K; idx += TPB) {
    int c = idx & 63, k4 = (idx >> 6) << 2;
    const float* p0 = W0 + (size_t)k4 * Nc + n0 + c;
    const float* p1 = W1 + (size_t)k4 * Nc + n0 + c;
    ushort4 pk0, pk1;
    pk0.x = f2bf(p0[0]); pk0.y = f2bf(p0[Nc]); pk0.z = f2bf(p0[2 * Nc]); pk0.w = f2bf(p0[3 * Nc]);
    pk1.x = f2bf(p1[0]); pk1.y = f2bf(p1[Nc]); pk1.z = f2bf(p1[2 * Nc]); pk1.w = f2bf(p1[3 * Nc]);
    int kb = (k4 * 2) ^ ((c & 7) << 4);
    *(ushort4*)((char*)Bls + c * Kb + kb) = pk0;
    *(ushort4*)((char*)Brs + c * Kb + kb) = pk1;
  }
  __syncthreads();

  // ---- MFMA K-loop: wave w owns rows w*16..w*16+15, cols n0..n0+63 for both W ----
  const int w = tid >> 6, lane = tid & 63;
  const int arow = w * 16 + (lane & 15);
  const int l16 = (lane >> 4) << 3;  // k sub-offset (8 bf16)
  f32x4 accL[4], accR[4];
#pragma unroll
  for (int i = 0; i < 4; ++i) { accL[i] = (f32x4)0.f; accR[i] = (f32x4)0.f; }
  for (int k0 = 0; k0 < K; k0 += 32) {
    int kb = (k0 + l16) * 2;
    bfrag8 af = *(bfrag8*)((char*)As + arow * Kb + (kb ^ ((arow & 7) << 4)));
#pragma unroll
    for (int cf = 0; cf < 4; ++cf) {
      int col = cf * 16 + (lane & 15);
      int cb = col * Kb + (kb ^ ((col & 7) << 4));
      bfrag8 bl = *(bfrag8*)((char*)Bls + cb);
      accL[cf] = __builtin_amdgcn_mfma_f32_16x16x32_bf16(af, bl, accL[cf], 0, 0, 0);
      bfrag8 br = *(bfrag8*)((char*)Brs + cb);
      accR[cf] = __builtin_amdgcn_mfma_f32_16x16x32_bf16(af, br, accR[cf], 0, 0, 0);
    }
  }
  // ---- epilogue: C/D map col=lane&15, row=(lane>>4)*4+reg ----
  const int rbase = r0 + w * 16 + ((lane >> 4) << 2);
  const int cbase = n0 + (lane & 15);
#pragma unroll
  for (int cf = 0; cf < 4; ++cf) {
    int gcol = cbase + cf * 16;
    float bb0 = b0[gcol], bb1 = b1[gcol];
#pragma unroll
    for (int r = 0; r < 4; ++r) {
      int grow = rbase + r;
      if (grow < M) {
        out0[(size_t)grow * Nc + gcol] = f2bf(accL[cf][r] + bb0);
        out1[(size_t)grow * Nc + gcol] = f2bf(accR[cf][r] + bb1);
      }
    }
  }
}

// ---------------- Fused GATv2 layer 1: H=4, C=64, wave/node, 4-edge unroll, max-free ----------------
__global__ void k_gat1(const unsigned short* __restrict__ xl,
                       const unsigned short* __restrict__ xr,
                       const int* __restrict__ rowoff, const int* __restrict__ csrc,
                       const float* __restrict__ att, const float* __restrict__ bias,
                       float* __restrict__ out, int N) {
  int node = (blockIdx.x * blockDim.x + threadIdx.x) >> 6;
  int lane = threadIdx.x & 63;
  if (node >= N) return;
  int l4 = lane * 4;
  uint2 rv = *(const uint2*)(xr + (size_t)node * 256 + l4);
  float xr0 = bf2f(rv.x & 0xffffu), xr1 = bf2f(rv.x >> 16);
  float xr2 = bf2f(rv.y & 0xffffu), xr3 = bf2f(rv.y >> 16);
  float4 at = *(const float4*)(att + l4);
  int beg = rowoff[node], end = rowoff[node + 1];
  float s = 0.f, a0 = 0.f, a1 = 0.f, a2 = 0.f, a3 = 0.f;
  int k = beg;
  for (; k + 4 <= end; k += 4) {
    int srcs[4];
#pragma unroll
    for (int u = 0; u < 4; ++u) srcs[u] = csrc[k + u];
    uint2 vv[4];
#pragma unroll
    for (int u = 0; u < 4; ++u) vv[u] = *(const uint2*)(xl + (size_t)srcs[u] * 256 + l4);
    float xs[4][4], ps[4];
#pragma unroll
    for (int u = 0; u < 4; ++u) {
      xs[u][0] = bf2f(vv[u].x & 0xffffu); xs[u][1] = bf2f(vv[u].x >> 16);
      xs[u][2] = bf2f(vv[u].y & 0xffffu); xs[u][3] = bf2f(vv[u].y >> 16);
      ps[u] = lrelu(xs[u][0] + xr0) * at.x + lrelu(xs[u][1] + xr1) * at.y
            + lrelu(xs[u][2] + xr2) * at.z + lrelu(xs[u][3] + xr3) * at.w;
    }
#pragma unroll
    for (int u = 0; u < 4; ++u) {
      ps[u] += __shfl_xor(ps[u], 1); ps[u] += __shfl_xor(ps[u], 2);
      ps[u] += __shfl_xor(ps[u], 4); ps[u] += __shfl_xor(ps[u], 8);
    }
#pragma unroll
    for (int u = 0; u < 4; ++u) {
      float w = __expf(ps[u]);
      s += w;
      a0 += w * xs[u][0]; a1 += w * xs[u][1];
      a2 += w * xs[u][2]; a3 += w * xs[u][3];
    }
  }
  for (; k < end; ++k) {
    int src = csrc[k];
    uint2 v = *(const uint2*)(xl + (size_t)src * 256 + l4);
    float x0 = bf2f(v.x & 0xffffu), x1 = bf2f(v.x >> 16);
    float x2 = bf2f(v.y & 0xffffu), x3 = bf2f(v.y >> 16);
    float p = lrelu(x0 + xr0) * at.x + lrelu(x1 + xr1) * at.y
            + lrelu(x2 + xr2) * at.z + lrelu(x3 + xr3) * at.w;
    p += __shfl_xor(p, 1); p += __shfl_xor(p, 2);
    p += __shfl_xor(p, 4); p += __shfl_xor(p, 8);
    float w = __expf(p);
    s += w;
    a0 += w * x0; a1 += w * x1; a2 += w * x2; a3 += w * x3;
  }
  float inv = 1.f / (s + 1e-16f);
  a0 *= inv; a1 *= inv; a2 *= inv; a3 *= inv;
  // mean over the 4 heads
  a0 += __shfl_xor(a0, 16); a0 += __shfl_xor(a0, 32);
  a1 += __shfl_xor(a1, 16); a1 += __shfl_xor(a1, 32);
  a2 += __shfl_xor(a2, 16); a2 += __shfl_xor(a2, 32);
  a3 += __shfl_xor(a3, 16); a3 += __shfl_xor(a3, 32);
  if (lane < 16) {
    float4 o;
    o.x = a0 * 0.25f + bias[l4 + 0];
    o.y = a1 * 0.25f + bias[l4 + 1];
    o.z = a2 * 0.25f + bias[l4 + 2];
    o.w = a3 * 0.25f + bias[l4 + 3];
    *(float4*)(out + (size_t)node * 64 + l4) = o;
  }
}

// ---------------- Fused GATv2 layer 2: H=1, C=64, 4 edges/wave (16 lanes each), max-free ----------------
__global__ void k_gat2(const unsigned short* __restrict__ xl,
                       const unsigned short* __restrict__ xr,
                       const int* __restrict__ rowoff, const int* __restrict__ csrc,
                       const float* __restrict__ att, const float* __restrict__ bias,
                       float* __restrict__ out, int N) {
  int node = (blockIdx.x * blockDim.x + threadIdx.x) >> 6;
  int lane = threadIdx.x & 63;
  if (node >= N) return;
  int grp = lane >> 4, c4 = (lane & 15) * 4;
  uint2 rv = *(const uint2*)(xr + (size_t)node * 64 + c4);
  float xr0 = bf2f(rv.x & 0xffffu), xr1 = bf2f(rv.x >> 16);
  float xr2 = bf2f(rv.y & 0xffffu), xr3 = bf2f(rv.y >> 16);
  float4 at = *(const float4*)(att + c4);
  int beg = rowoff[node], end = rowoff[node + 1];
  int iters = (end - beg + 3) >> 2;
  float s = 0.f, a0 = 0.f, a1 = 0.f, a2 = 0.f, a3 = 0.f;
  for (int it = 0; it < iters; ++it) {
    int kk = beg + it * 4 + grp;
    bool ok = kk < end;
    int src = ok ? csrc[kk] : 0;
    uint2 v = *(const uint2*)(xl + (size_t)src * 64 + c4);
    float x0 = bf2f(v.x & 0xffffu), x1 = bf2f(v.x >> 16);
    float x2 = bf2f(v.y & 0xffffu), x3 = bf2f(v.y >> 16);
    float p = lrelu(x0 + xr0) * at.x + lrelu(x1 + xr1) * at.y
            + lrelu(x2 + xr2) * at.z + lrelu(x3 + xr3) * at.w;
    p += __shfl_xor(p, 1); p += __shfl_xor(p, 2);
    p += __shfl_xor(p, 4); p += __shfl_xor(p, 8);
    float w = ok ? __expf(p) : 0.f;
    s += w;
    a0 += w * x0; a1 += w * x1; a2 += w * x2; a3 += w * x3;
  }
  // sum the 4 edge-groups
  s  += __shfl_xor(s, 16);  s  += __shfl_xor(s, 32);
  a0 += __shfl_xor(a0, 16); a0 += __shfl_xor(a0, 32);
  a1 += __shfl_xor(a1, 16); a1 += __shfl_xor(a1, 32);
  a2 += __shfl_xor(a2, 16); a2 += __shfl_xor(a2, 32);
  a3 += __shfl_xor(a3, 16); a3 += __shfl_xor(a3, 32);
  if (lane < 16) {
    float inv = 1.f / (s + 1e-16f);
    float4 o;
    o.x = a0 * inv + bias[c4 + 0];
    o.y = a1 * inv + bias[c4 + 1];
    o.z = a2 * inv + bias[c4 + 2];
    o.w = a3 * inv + bias[c4 + 3];
    *(float4*)(out + (size_t)node * 64 + c4) = o;
  }
}

// ---------------- BatchNorm ----------------
__global__ void k_bnstat(const float* __restrict__ in, int N, float* __restrict__ part) {
  __shared__ float sm[TPB], sq[TPB];
  int col = threadIdx.x & 63;
  int rq = threadIdx.x >> 6;
  float s = 0.f, q = 0.f;
  for (int r = blockIdx.x * 4 + rq; r < N; r += gridDim.x * 4) {
    float v = in[(size_t)r * 64 + col];
    s += v; q += v * v;
  }
  sm[threadIdx.x] = s; sq[threadIdx.x] = q;
  __syncthreads();
  if (threadIdx.x < 64) {
    s = sm[threadIdx.x] + sm[threadIdx.x + 64] + sm[threadIdx.x + 128] + sm[threadIdx.x + 192];
    q = sq[threadIdx.x] + sq[threadIdx.x + 64] + sq[threadIdx.x + 128] + sq[threadIdx.x + 192];
    part[(size_t)blockIdx.x * 128 + threadIdx.x] = s;
    part[(size_t)blockIdx.x * 128 + 64 + threadIdx.x] = q;
  }
}

__global__ void k_bnfin(const float* __restrict__ part, int B, int N,
                        const float* __restrict__ g, const float* __restrict__ beta,
                        float* __restrict__ ab) {
  int c = threadIdx.x;  // 64 threads
  float s = 0.f, q = 0.f;
  for (int b = 0; b < B; ++b) {
    s += part[(size_t)b * 128 + c];
    q += part[(size_t)b * 128 + 64 + c];
  }
  float mean = s / (float)N;
  float var = q / (float)N - mean * mean;
  float a = g[c] * rsqrtf(var + 1e-5f);
  ab[c] = a;
  ab[64 + c] = beta[c] - mean * a;
}

__global__ void k_bnapply(const float* __restrict__ in, const float* __restrict__ ab,
                          float* __restrict__ out, int total4) {
  int idx = blockIdx.x * blockDim.x + threadIdx.x;
  if (idx >= total4) return;
  float4 v = *(const float4*)(in + (size_t)idx * 4);
  int c0 = (idx & 15) * 4;
  v.x = fmaxf(v.x * ab[c0 + 0] + ab[64 + c0 + 0], 0.f);
  v.y = fmaxf(v.y * ab[c0 + 1] + ab[64 + c0 + 1], 0.f);
  v.z = fmaxf(v.z * ab[c0 + 2] + ab[64 + c0 + 2], 0.f);
  v.w = fmaxf(v.w * ab[c0 + 3] + ab[64 + c0 + 3], 0.f);
  *(float4*)(out + (size_t)idx * 4) = v;
}

extern "C" void kernel_launch(void* const* d_in, const int* in_sizes, int n_in,
                              void* d_out, int out_size, void* d_ws, size_t ws_size,
                              hipStream_t stream) {
  const float* x     = (const float*)d_in[0];
  const int*   ei    = (const int*)d_in[1];
  const float* Wl1   = (const float*)d_in[2];
  const float* bl1   = (const float*)d_in[3];
  const float* Wr1   = (const float*)d_in[4];
  const float* br1   = (const float*)d_in[5];
  const float* att1  = (const float*)d_in[6];
  const float* bias1 = (const float*)d_in[7];
  const float* g1    = (const float*)d_in[8];
  const float* be1   = (const float*)d_in[9];
  const float* Wl2   = (const float*)d_in[10];
  const float* bl2   = (const float*)d_in[11];
  const float* Wr2   = (const float*)d_in[12];
  const float* br2   = (const float*)d_in[13];
  const float* att2  = (const float*)d_in[14];
  const float* bias2 = (const float*)d_in[15];
  const float* g2    = (const float*)d_in[16];
  const float* be2   = (const float*)d_in[17];
  float* out = (float*)d_out;

  const int N  = in_sizes[0] / 128;   // 50000
  const int E  = in_sizes[1] / 2;     // 800000
  const int ET = E + N;               // + self loops
  const int SB = (N + TPB - 1) / TPB; // 196 (<= TPB, required by k_scan2)

  char* p = (char*)d_ws;
  auto take = [&](size_t b) { char* q = p; p += (b + 255) & ~(size_t)255; return q; };

  unsigned short* xl1 = (unsigned short*)take((size_t)N * 256 * 2);
  unsigned short* xr1 = (unsigned short*)take((size_t)N * 256 * 2);
  unsigned short* xl2 = (unsigned short*)take((size_t)N * 64 * 2);
  unsigned short* xr2 = (unsigned short*)take((size_t)N * 64 * 2);
  float* out1 = (float*)take((size_t)N * 64 * 4);
  int* deg    = (int*)take((size_t)N * 4);
  int* rowoff = (int*)take((size_t)(N + 1) * 4);
  int* cursor = (int*)take((size_t)N * 4);
  int* csrc   = (int*)take((size_t)ET * 4);
  int* bsum   = (int*)take((size_t)SB * 4);
  int* bpre   = (int*)take((size_t)SB * 4);
  float* part = (float*)take((size_t)128 * 128 * 4);
  float* ab1  = (float*)take(128 * 4);
  float* ab2  = (float*)take(128 * 4);
  (void)ws_size; (void)n_in; (void)out_size;

  int egrid = (ET + TPB - 1) / TPB;
  int ngrid = (N + 3) / 4;           // 4 wave-nodes per block
  int mtile = (N + 63) / 64;         // 782
  int total4 = N * 16;               // N*64/4

  // CSR build
  hipMemsetAsync(deg, 0, (size_t)N * 4, stream);
  k_deg<<<egrid, TPB, 0, stream>>>(ei, E, ET, deg);
  k_scan1<<<SB, TPB, 0, stream>>>(deg, N, bsum);
  k_scan2<<<1, TPB, 0, stream>>>(bsum, SB, bpre, rowoff, N);
  k_scan3<<<SB, TPB, 0, stream>>>(deg, bpre, N, rowoff, cursor);
  k_fill<<<egrid, TPB, 0, stream>>>(ei, E, ET, cursor, csrc);

  // Layer 1: fused xl1/xr1 GEMM (bf16 MFMA), then GAT, then BN stats
  k_gemm_mfma<<<dim3(mtile, 4), TPB, 0, stream>>>(x, Wl1, bl1, Wr1, br1, xl1, xr1,
                                                  N, 128, 256, nullptr);
  k_gat1<<<ngrid, TPB, 0, stream>>>(xl1, xr1, rowoff, csrc, att1, bias1, out1, N);
  k_bnstat<<<128, TPB, 0, stream>>>(out1, N, part);
  k_bnfin<<<1, 64, 0, stream>>>(part, 128, N, g1, be1, ab1);

  // Layer 2: BN+ReLU fused into GEMM A-staging (affine=ab1)
  k_gemm_mfma<<<dim3(mtile, 1), TPB, 0, stream>>>(out1, Wl2, bl2, Wr2, br2, xl2, xr2,
                                                  N, 64, 64, ab1);
  k_gat2<<<ngrid, TPB, 0, stream>>>(xl2, xr2, rowoff, csrc, att2, bias2, out, N);
  k_bnstat<<<128, TPB, 0, stream>>>(out, N, part);
  k_bnfin<<<1, 64, 0, stream>>>(part, 128, N, g2, be2, ab2);
  k_bnapply<<<(total4 + TPB - 1) / TPB, TPB, 0, stream>>>(out, ab2, out, total4);
}

// Round 3
// 405.133 us; speedup vs baseline: 1.6657x; 1.0043x over previous
//
#include <hip/hip_runtime.h>
#include <hip/hip_bf16.h>
#include <math.h>

#define TPB 256

typedef __attribute__((ext_vector_type(8))) short bfrag8;
typedef __attribute__((ext_vector_type(4))) float f32x4;

static __device__ __forceinline__ float bf2f(unsigned int u) {
  union { unsigned int i; float f; } c; c.i = u << 16; return c.f;
}
static __device__ __forceinline__ unsigned short f2bf(float f) {
  union { float f; unsigned int i; } c; c.f = f;
  unsigned int lsb = (c.i >> 16) & 1u;
  return (unsigned short)((c.i + 0x7fffu + lsb) >> 16);
}

// ---------------- CSR build ----------------
__global__ void k_deg(const int* __restrict__ ei, int E, int ET, int* __restrict__ deg) {
  int e = blockIdx.x * blockDim.x + threadIdx.x;
  if (e >= ET) return;
  int dst = (e < E) ? ei[E + e] : (e - E);
  atomicAdd(&deg[dst], 1);
}

__global__ void k_scan1(const int* __restrict__ deg, int N, int* __restrict__ bsum) {
  __shared__ int sm[TPB];
  int i = blockIdx.x * TPB + threadIdx.x;
  sm[threadIdx.x] = (i < N) ? deg[i] : 0;
  __syncthreads();
  for (int d = TPB / 2; d > 0; d >>= 1) {
    if (threadIdx.x < d) sm[threadIdx.x] += sm[threadIdx.x + d];
    __syncthreads();
  }
  if (threadIdx.x == 0) bsum[blockIdx.x] = sm[0];
}

// requires SB <= TPB (N <= 65536)
__global__ void k_scan3(const int* __restrict__ deg, const int* __restrict__ bsum,
                        int SB, int N, int* __restrict__ rowoff, int* __restrict__ cursor) {
  __shared__ int sm[TPB];
  // base = sum of bsum[0..bid)
  int pv = (threadIdx.x < blockIdx.x) ? bsum[threadIdx.x] : 0;
  sm[threadIdx.x] = pv;
  __syncthreads();
  for (int dd = TPB / 2; dd > 0; dd >>= 1) {
    if (threadIdx.x < dd) sm[threadIdx.x] += sm[threadIdx.x + dd];
    __syncthreads();
  }
  int base = sm[0];
  __syncthreads();
  // inclusive scan of this block's degrees
  int i = blockIdx.x * TPB + threadIdx.x;
  int v = (i < N) ? deg[i] : 0;
  sm[threadIdx.x] = v;
  __syncthreads();
  for (int dd = 1; dd < TPB; dd <<= 1) {
    int t = (threadIdx.x >= dd) ? sm[threadIdx.x - dd] : 0;
    __syncthreads();
    sm[threadIdx.x] += t;
    __syncthreads();
  }
  if (i < N) {
    int off = base + sm[threadIdx.x] - v;  // exclusive
    rowoff[i] = off;
    cursor[i] = off;
  }
  if (blockIdx.x == SB - 1 && threadIdx.x == TPB - 1) rowoff[N] = base + sm[TPB - 1];
}

__global__ void k_fill(const int* __restrict__ ei, int E, int ET,
                       int* __restrict__ cursor, int* __restrict__ csrc) {
  int e = blockIdx.x * blockDim.x + threadIdx.x;
  if (e >= ET) return;
  int src, dst;
  if (e < E) { src = ei[e]; dst = ei[E + e]; } else { src = dst = e - E; }
  int pos = atomicAdd(&cursor[dst], 1);
  csrc[pos] = src;
}

// ---------------- prep: f32 -> bf16 conversions (x, transposed W's) ----------------
__global__ void k_prep1(const float* __restrict__ x,
                        const float* __restrict__ Wl1, const float* __restrict__ Wr1,
                        const float* __restrict__ Wl2, const float* __restrict__ Wr2,
                        unsigned short* __restrict__ xb,
                        unsigned short* __restrict__ wt1l, unsigned short* __restrict__ wt1r,
                        unsigned short* __restrict__ wt2l, unsigned short* __restrict__ wt2r,
                        int nx4) {
  int i = blockIdx.x * blockDim.x + threadIdx.x;
  int stride = gridDim.x * blockDim.x;
  int wtot = nx4 + 65536 + 8192;
  for (; i < wtot; i += stride) {
    if (i < nx4) {
      float4 v = *(const float4*)(x + (size_t)i * 4);
      ushort4 o; o.x = f2bf(v.x); o.y = f2bf(v.y); o.z = f2bf(v.z); o.w = f2bf(v.w);
      *(ushort4*)(xb + (size_t)i * 4) = o;
    } else if (i < nx4 + 32768) {
      int j = i - nx4; int c = j >> 7, k = j & 127;
      wt1l[j] = f2bf(Wl1[(size_t)k * 256 + c]);
    } else if (i < nx4 + 65536) {
      int j = i - nx4 - 32768; int c = j >> 7, k = j & 127;
      wt1r[j] = f2bf(Wr1[(size_t)k * 256 + c]);
    } else if (i < nx4 + 65536 + 4096) {
      int j = i - nx4 - 65536; int c = j >> 6, k = j & 63;
      wt2l[j] = f2bf(Wl2[(size_t)k * 64 + c]);
    } else {
      int j = i - nx4 - 69632; int c = j >> 6, k = j & 63;
      wt2r[j] = f2bf(Wr2[(size_t)k * 64 + c]);
    }
  }
}

// prep2: BN affine + relu + bf16 (layer-2 GEMM input)
__global__ void k_prep2(const float* __restrict__ in, const float* __restrict__ ab,
                        unsigned short* __restrict__ o, int n4) {
  int i = blockIdx.x * blockDim.x + threadIdx.x;
  if (i >= n4) return;
  float4 v = *(const float4*)(in + (size_t)i * 4);
  int c0 = (i & 15) * 4;
  ushort4 u;
  u.x = f2bf(fmaxf(v.x * ab[c0 + 0] + ab[64 + c0 + 0], 0.f));
  u.y = f2bf(fmaxf(v.y * ab[c0 + 1] + ab[64 + c0 + 1], 0.f));
  u.z = f2bf(fmaxf(v.z * ab[c0 + 2] + ab[64 + c0 + 2], 0.f));
  u.w = f2bf(fmaxf(v.w * ab[c0 + 3] + ab[64 + c0 + 3], 0.f));
  *(ushort4*)(o + (size_t)i * 4) = u;
}

// ---------------- MFMA GEMM (bf16 in): out{0,1} = Ab @ Wt{0,1}^T + b{0,1} ----------------
// Also emits dl/dr: 0.6 * (att-dot of each output row per head). LDS XOR-swizzled (T2).
__global__ void k_gemm_mfma(const unsigned short* __restrict__ Ab,
                            const unsigned short* __restrict__ Wt0, const float* __restrict__ b0,
                            const unsigned short* __restrict__ Wt1, const float* __restrict__ b1,
                            const float* __restrict__ att,
                            float* __restrict__ dl, float* __restrict__ dr,
                            unsigned short* __restrict__ out0, unsigned short* __restrict__ out1,
                            int M, int K, int Nc, int Hs) {
  extern __shared__ short lds[];
  short* As = lds;
  short* Bls = lds + 64 * K;
  short* Brs = lds + 128 * K;
  const int r0 = blockIdx.x * 64, n0 = blockIdx.y * 64;
  const int tid = threadIdx.x;
  const int Kb = K * 2;
  const int cpr = K >> 3;          // 16B chunks per row
  const int chunks = 64 * cpr;
  for (int idx = tid; idx < chunks; idx += TPB) {
    int row = idx / cpr, k8 = (idx - row * cpr) * 8;
    int kb = (k8 * 2) ^ ((row & 7) << 4);
    int gr = r0 + row;
    uint4 av = make_uint4(0, 0, 0, 0);
    if (gr < M) av = *(const uint4*)(Ab + (size_t)gr * K + k8);
    *(uint4*)((char*)As + row * Kb + kb) = av;
    uint4 w0 = *(const uint4*)(Wt0 + (size_t)(n0 + row) * K + k8);
    *(uint4*)((char*)Bls + row * Kb + kb) = w0;
    uint4 w1 = *(const uint4*)(Wt1 + (size_t)(n0 + row) * K + k8);
    *(uint4*)((char*)Brs + row * Kb + kb) = w1;
  }
  __syncthreads();

  const int w = tid >> 6, lane = tid & 63;
  const int arow = w * 16 + (lane & 15);
  const int l16 = (lane >> 4) << 3;
  f32x4 accL[4], accR[4];
#pragma unroll
  for (int i = 0; i < 4; ++i) { accL[i] = (f32x4)0.f; accR[i] = (f32x4)0.f; }
  for (int k0 = 0; k0 < K; k0 += 32) {
    int kb = (k0 + l16) * 2;
    bfrag8 af = *(bfrag8*)((char*)As + arow * Kb + (kb ^ ((arow & 7) << 4)));
#pragma unroll
    for (int cf = 0; cf < 4; ++cf) {
      int col = cf * 16 + (lane & 15);
      int cb = col * Kb + (kb ^ ((col & 7) << 4));
      bfrag8 bl = *(bfrag8*)((char*)Bls + cb);
      accL[cf] = __builtin_amdgcn_mfma_f32_16x16x32_bf16(af, bl, accL[cf], 0, 0, 0);
      bfrag8 br = *(bfrag8*)((char*)Brs + cb);
      accR[cf] = __builtin_amdgcn_mfma_f32_16x16x32_bf16(af, br, accR[cf], 0, 0, 0);
    }
  }
  // epilogue: C/D map col=lane&15, row=(lane>>4)*4+reg
  const int rbase = r0 + w * 16 + ((lane >> 4) << 2);
  const int cbase = n0 + (lane & 15);
  float tL[4] = {0.f, 0.f, 0.f, 0.f}, tR[4] = {0.f, 0.f, 0.f, 0.f};
#pragma unroll
  for (int cf = 0; cf < 4; ++cf) {
    int gcol = cbase + cf * 16;
    float bb0 = b0[gcol], bb1 = b1[gcol], aa = att[gcol];
#pragma unroll
    for (int r = 0; r < 4; ++r) {
      float oL = accL[cf][r] + bb0, oR = accR[cf][r] + bb1;
      int grow = rbase + r;
      if (grow < M) {
        out0[(size_t)grow * Nc + gcol] = f2bf(oL);
        out1[(size_t)grow * Nc + gcol] = f2bf(oR);
      }
      tL[r] += oL * aa;
      tR[r] += oR * aa;
    }
  }
#pragma unroll
  for (int r = 0; r < 4; ++r) {
#pragma unroll
    for (int d = 1; d < 16; d <<= 1) {
      tL[r] += __shfl_xor(tL[r], d);
      tR[r] += __shfl_xor(tR[r], d);
    }
  }
  if ((lane & 15) == 0) {
    int h = n0 >> 6;
#pragma unroll
    for (int r = 0; r < 4; ++r) {
      int grow = rbase + r;
      if (grow < M) {
        dl[(size_t)grow * Hs + h] = 0.6f * tL[r];
        dr[(size_t)grow * Hs + h] = 0.6f * tR[r];
      }
    }
  }
}

// ---------------- GATv2 layer 1: H=4, C=64; p = dl[src]+dr[dst]+0.4*att.|xl+xr| ----------------
__global__ void k_gat1(const unsigned short* __restrict__ xl,
                       const unsigned short* __restrict__ xr,
                       const float* __restrict__ dl, const float* __restrict__ dr,
                       const int* __restrict__ rowoff, const int* __restrict__ csrc,
                       const float* __restrict__ att, const float* __restrict__ bias,
                       float* __restrict__ out, int N, int nw) {
  int wid = (blockIdx.x * blockDim.x + threadIdx.x) >> 6;
  int lane = threadIdx.x & 63;
  int l4 = lane * 4, hid = lane >> 4;
  float4 atv = *(const float4*)(att + l4);
  float atx = 0.4f * atv.x, aty = 0.4f * atv.y, atz = 0.4f * atv.z, atw = 0.4f * atv.w;
  float4 bb = *(const float4*)(bias + l4);
  for (int node = wid; node < N; node += nw) {
    uint2 rv = *(const uint2*)(xr + (size_t)node * 256 + l4);
    float xr0 = bf2f(rv.x & 0xffffu), xr1 = bf2f(rv.x >> 16);
    float xr2 = bf2f(rv.y & 0xffffu), xr3 = bf2f(rv.y >> 16);
    float drv = dr[node * 4 + hid];
    int beg = rowoff[node], end = rowoff[node + 1];
    float s = 0.f, a0 = 0.f, a1 = 0.f, a2 = 0.f, a3 = 0.f;
    int k = beg;
    for (; k + 4 <= end; k += 4) {
      int srcs[4]; uint2 vv[4]; float dls[4], ps[4];
#pragma unroll
      for (int u = 0; u < 4; ++u) srcs[u] = csrc[k + u];
#pragma unroll
      for (int u = 0; u < 4; ++u) {
        vv[u] = *(const uint2*)(xl + (size_t)srcs[u] * 256 + l4);
        dls[u] = dl[srcs[u] * 4 + hid];
      }
#pragma unroll
      for (int u = 0; u < 4; ++u) {
        float x0 = bf2f(vv[u].x & 0xffffu), x1 = bf2f(vv[u].x >> 16);
        float x2 = bf2f(vv[u].y & 0xffffu), x3 = bf2f(vv[u].y >> 16);
        ps[u] = atx * fabsf(x0 + xr0) + aty * fabsf(x1 + xr1)
              + atz * fabsf(x2 + xr2) + atw * fabsf(x3 + xr3);
      }
#pragma unroll
      for (int u = 0; u < 4; ++u) {
        ps[u] += __shfl_xor(ps[u], 1); ps[u] += __shfl_xor(ps[u], 2);
        ps[u] += __shfl_xor(ps[u], 4); ps[u] += __shfl_xor(ps[u], 8);
      }
#pragma unroll
      for (int u = 0; u < 4; ++u) {
        float wv = __expf(ps[u] + dls[u] + drv);
        float x0 = bf2f(vv[u].x & 0xffffu), x1 = bf2f(vv[u].x >> 16);
        float x2 = bf2f(vv[u].y & 0xffffu), x3 = bf2f(vv[u].y >> 16);
        s += wv; a0 += wv * x0; a1 += wv * x1; a2 += wv * x2; a3 += wv * x3;
      }
    }
    if (k < end) {  // predicated tail quad
      int srcs[4]; uint2 vv[4]; float dls[4], ps[4]; bool okv[4];
#pragma unroll
      for (int u = 0; u < 4; ++u) {
        okv[u] = (k + u) < end;
        srcs[u] = okv[u] ? csrc[k + u] : 0;
      }
#pragma unroll
      for (int u = 0; u < 4; ++u) {
        vv[u] = *(const uint2*)(xl + (size_t)srcs[u] * 256 + l4);
        dls[u] = dl[srcs[u] * 4 + hid];
      }
#pragma unroll
      for (int u = 0; u < 4; ++u) {
        float x0 = bf2f(vv[u].x & 0xffffu), x1 = bf2f(vv[u].x >> 16);
        float x2 = bf2f(vv[u].y & 0xffffu), x3 = bf2f(vv[u].y >> 16);
        ps[u] = atx * fabsf(x0 + xr0) + aty * fabsf(x1 + xr1)
              + atz * fabsf(x2 + xr2) + atw * fabsf(x3 + xr3);
      }
#pragma unroll
      for (int u = 0; u < 4; ++u) {
        ps[u] += __shfl_xor(ps[u], 1); ps[u] += __shfl_xor(ps[u], 2);
        ps[u] += __shfl_xor(ps[u], 4); ps[u] += __shfl_xor(ps[u], 8);
      }
#pragma unroll
      for (int u = 0; u < 4; ++u) {
        float wv = okv[u] ? __expf(ps[u] + dls[u] + drv) : 0.f;
        float x0 = bf2f(vv[u].x & 0xffffu), x1 = bf2f(vv[u].x >> 16);
        float x2 = bf2f(vv[u].y & 0xffffu), x3 = bf2f(vv[u].y >> 16);
        s += wv; a0 += wv * x0; a1 += wv * x1; a2 += wv * x2; a3 += wv * x3;
      }
    }
    float inv = 1.f / (s + 1e-16f);
    a0 *= inv; a1 *= inv; a2 *= inv; a3 *= inv;
    a0 += __shfl_xor(a0, 16); a0 += __shfl_xor(a0, 32);
    a1 += __shfl_xor(a1, 16); a1 += __shfl_xor(a1, 32);
    a2 += __shfl_xor(a2, 16); a2 += __shfl_xor(a2, 32);
    a3 += __shfl_xor(a3, 16); a3 += __shfl_xor(a3, 32);
    if (lane < 16) {
      float4 o;
      o.x = a0 * 0.25f + bb.x;
      o.y = a1 * 0.25f + bb.y;
      o.z = a2 * 0.25f + bb.z;
      o.w = a3 * 0.25f + bb.w;
      *(float4*)(out + (size_t)node * 64 + l4) = o;
    }
  }
}

// ---------------- GATv2 layer 2: H=1, C=64; 4 edges/wave ----------------
__global__ void k_gat2(const unsigned short* __restrict__ xl,
                       const unsigned short* __restrict__ xr,
                       const float* __restrict__ dl, const float* __restrict__ dr,
                       const int* __restrict__ rowoff, const int* __restrict__ csrc,
                       const float* __restrict__ att, const float* __restrict__ bias,
                       float* __restrict__ out, int N, int nw) {
  int wid = (blockIdx.x * blockDim.x + threadIdx.x) >> 6;
  int lane = threadIdx.x & 63;
  int grp = lane >> 4, c4 = (lane & 15) * 4;
  float4 atv = *(const float4*)(att + c4);
  float atx = 0.4f * atv.x, aty = 0.4f * atv.y, atz = 0.4f * atv.z, atw = 0.4f * atv.w;
  float4 bb = *(const float4*)(bias + c4);
  for (int node = wid; node < N; node += nw) {
    uint2 rv = *(const uint2*)(xr + (size_t)node * 64 + c4);
    float xr0 = bf2f(rv.x & 0xffffu), xr1 = bf2f(rv.x >> 16);
    float xr2 = bf2f(rv.y & 0xffffu), xr3 = bf2f(rv.y >> 16);
    float drv = dr[node];
    int beg = rowoff[node], end = rowoff[node + 1];
    int nf = (end - beg) >> 2;
    float s = 0.f, a0 = 0.f, a1 = 0.f, a2 = 0.f, a3 = 0.f;
    for (int it = 0; it < nf; ++it) {
      int kk = beg + it * 4 + grp;
      int src = csrc[kk];
      float dlv = dl[src];
      uint2 v = *(const uint2*)(xl + (size_t)src * 64 + c4);
      float x0 = bf2f(v.x & 0xffffu), x1 = bf2f(v.x >> 16);
      float x2 = bf2f(v.y & 0xffffu), x3 = bf2f(v.y >> 16);
      float p = atx * fabsf(x0 + xr0) + aty * fabsf(x1 + xr1)
              + atz * fabsf(x2 + xr2) + atw * fabsf(x3 + xr3);
      p += __shfl_xor(p, 1); p += __shfl_xor(p, 2);
      p += __shfl_xor(p, 4); p += __shfl_xor(p, 8);
      float wv = __expf(p + dlv + drv);
      s += wv; a0 += wv * x0; a1 += wv * x1; a2 += wv * x2; a3 += wv * x3;
    }
    if ((end - beg) & 3) {  // predicated tail
      int kk = beg + nf * 4 + grp;
      bool ok = kk < end;
      int src = ok ? csrc[kk] : 0;
      float dlv = dl[src];
      uint2 v = *(const uint2*)(xl + (size_t)src * 64 + c4);
      float x0 = bf2f(v.x & 0xffffu), x1 = bf2f(v.x >> 16);
      float x2 = bf2f(v.y & 0xffffu), x3 = bf2f(v.y >> 16);
      float p = atx * fabsf(x0 + xr0) + aty * fabsf(x1 + xr1)
              + atz * fabsf(x2 + xr2) + atw * fabsf(x3 + xr3);
      p += __shfl_xor(p, 1); p += __shfl_xor(p, 2);
      p += __shfl_xor(p, 4); p += __shfl_xor(p, 8);
      float wv = ok ? __expf(p + dlv + drv) : 0.f;
      s += wv; a0 += wv * x0; a1 += wv * x1; a2 += wv * x2; a3 += wv * x3;
    }
    s  += __shfl_xor(s, 16);  s  += __shfl_xor(s, 32);
    a0 += __shfl_xor(a0, 16); a0 += __shfl_xor(a0, 32);
    a1 += __shfl_xor(a1, 16); a1 += __shfl_xor(a1, 32);
    a2 += __shfl_xor(a2, 16); a2 += __shfl_xor(a2, 32);
    a3 += __shfl_xor(a3, 16); a3 += __shfl_xor(a3, 32);
    if (lane < 16) {
      float inv = 1.f / (s + 1e-16f);
      float4 o;
      o.x = a0 * inv + bb.x;
      o.y = a1 * inv + bb.y;
      o.z = a2 * inv + bb.z;
      o.w = a3 * inv + bb.w;
      *(float4*)(out + (size_t)node * 64 + c4) = o;
    }
  }
}

// ---------------- BatchNorm ----------------
__global__ void k_bnstat(const float* __restrict__ in, int N, float* __restrict__ part) {
  __shared__ float sm[TPB], sq[TPB];
  int col = threadIdx.x & 63;
  int rq = threadIdx.x >> 6;
  float s = 0.f, q = 0.f;
  for (int r = blockIdx.x * 4 + rq; r < N; r += gridDim.x * 4) {
    float v = in[(size_t)r * 64 + col];
    s += v; q += v * v;
  }
  sm[threadIdx.x] = s; sq[threadIdx.x] = q;
  __syncthreads();
  if (threadIdx.x < 64) {
    s = sm[threadIdx.x] + sm[threadIdx.x + 64] + sm[threadIdx.x + 128] + sm[threadIdx.x + 192];
    q = sq[threadIdx.x] + sq[threadIdx.x + 64] + sq[threadIdx.x + 128] + sq[threadIdx.x + 192];
    part[(size_t)blockIdx.x * 128 + threadIdx.x] = s;
    part[(size_t)blockIdx.x * 128 + 64 + threadIdx.x] = q;
  }
}

__global__ void k_bnfin(const float* __restrict__ part, int B, int N,
                        const float* __restrict__ g, const float* __restrict__ beta,
                        float* __restrict__ ab) {
  int c = threadIdx.x;  // 64 threads
  float s = 0.f, q = 0.f;
  for (int b = 0; b < B; ++b) {
    s += part[(size_t)b * 128 + c];
    q += part[(size_t)b * 128 + 64 + c];
  }
  float mean = s / (float)N;
  float var = q / (float)N - mean * mean;
  float a = g[c] * rsqrtf(var + 1e-5f);
  ab[c] = a;
  ab[64 + c] = beta[c] - mean * a;
}

__global__ void k_bnapply(const float* __restrict__ in, const float* __restrict__ ab,
                          float* __restrict__ out, int total4) {
  int idx = blockIdx.x * blockDim.x + threadIdx.x;
  if (idx >= total4) return;
  float4 v = *(const float4*)(in + (size_t)idx * 4);
  int c0 = (idx & 15) * 4;
  v.x = fmaxf(v.x * ab[c0 + 0] + ab[64 + c0 + 0], 0.f);
  v.y = fmaxf(v.y * ab[c0 + 1] + ab[64 + c0 + 1], 0.f);
  v.z = fmaxf(v.z * ab[c0 + 2] + ab[64 + c0 + 2], 0.f);
  v.w = fmaxf(v.w * ab[c0 + 3] + ab[64 + c0 + 3], 0.f);
  *(float4*)(out + (size_t)idx * 4) = v;
}

extern "C" void kernel_launch(void* const* d_in, const int* in_sizes, int n_in,
                              void* d_out, int out_size, void* d_ws, size_t ws_size,
                              hipStream_t stream) {
  const float* x     = (const float*)d_in[0];
  const int*   ei    = (const int*)d_in[1];
  const float* Wl1   = (const float*)d_in[2];
  const float* bl1   = (const float*)d_in[3];
  const float* Wr1   = (const float*)d_in[4];
  const float* br1   = (const float*)d_in[5];
  const float* att1  = (const float*)d_in[6];
  const float* bias1 = (const float*)d_in[7];
  const float* g1    = (const float*)d_in[8];
  const float* be1   = (const float*)d_in[9];
  const float* Wl2   = (const float*)d_in[10];
  const float* bl2   = (const float*)d_in[11];
  const float* Wr2   = (const float*)d_in[12];
  const float* br2   = (const float*)d_in[13];
  const float* att2  = (const float*)d_in[14];
  const float* bias2 = (const float*)d_in[15];
  const float* g2    = (const float*)d_in[16];
  const float* be2   = (const float*)d_in[17];
  float* out = (float*)d_out;

  const int N  = in_sizes[0] / 128;   // 50000
  const int E  = in_sizes[1] / 2;     // 800000
  const int ET = E + N;
  const int SB = (N + TPB - 1) / TPB; // 196 (<= TPB required)

  char* p = (char*)d_ws;
  auto take = [&](size_t b) { char* q = p; p += (b + 255) & ~(size_t)255; return q; };

  unsigned short* xl1 = (unsigned short*)take((size_t)N * 256 * 2);
  unsigned short* xr1 = (unsigned short*)take((size_t)N * 256 * 2);
  unsigned short* xl2 = (unsigned short*)take((size_t)N * 64 * 2);
  unsigned short* xr2 = (unsigned short*)take((size_t)N * 64 * 2);
  float* out1 = (float*)take((size_t)N * 64 * 4);
  unsigned short* xb = (unsigned short*)take((size_t)N * 128 * 2);  // also reused as A2
  unsigned short* wt1l = (unsigned short*)take(256 * 128 * 2);
  unsigned short* wt1r = (unsigned short*)take(256 * 128 * 2);
  unsigned short* wt2l = (unsigned short*)take(64 * 64 * 2);
  unsigned short* wt2r = (unsigned short*)take(64 * 64 * 2);
  float* dl1 = (float*)take((size_t)N * 4 * 4);
  float* dr1 = (float*)take((size_t)N * 4 * 4);
  float* dl2 = (float*)take((size_t)N * 4);
  float* dr2 = (float*)take((size_t)N * 4);
  int* deg    = (int*)take((size_t)N * 4);
  int* rowoff = (int*)take((size_t)(N + 1) * 4);
  int* cursor = (int*)take((size_t)N * 4);
  int* csrc   = (int*)take((size_t)ET * 4);
  int* bsum   = (int*)take((size_t)SB * 4);
  float* part = (float*)take((size_t)128 * 128 * 4);
  float* ab1  = (float*)take(128 * 4);
  float* ab2  = (float*)take(128 * 4);
  (void)ws_size; (void)n_in; (void)out_size;

  unsigned short* A2 = xb;  // layer-2 GEMM input aliases xb (xb dead after gemm1)

  int egrid = (ET + TPB - 1) / TPB;
  int mtile = (N + 63) / 64;          // 782
  int total4 = N * 16;
  int nx4 = N * 32;                   // N*128/4
  int wtot = nx4 + 65536 + 8192;
  const int GATB = 2048, NW = GATB * (TPB / 64);

  // CSR build
  hipMemsetAsync(deg, 0, (size_t)N * 4, stream);
  k_deg<<<egrid, TPB, 0, stream>>>(ei, E, ET, deg);
  k_scan1<<<SB, TPB, 0, stream>>>(deg, N, bsum);
  k_scan3<<<SB, TPB, 0, stream>>>(deg, bsum, SB, N, rowoff, cursor);
  k_fill<<<egrid, TPB, 0, stream>>>(ei, E, ET, cursor, csrc);

  // prep: bf16 conversions
  k_prep1<<<(wtot + TPB - 1) / TPB, TPB, 0, stream>>>(x, Wl1, Wr1, Wl2, Wr2,
                                                      xb, wt1l, wt1r, wt2l, wt2r, nx4);

  // Layer 1
  k_gemm_mfma<<<dim3(mtile, 4), TPB, 3 * 64 * 128 * 2, stream>>>(
      xb, wt1l, bl1, wt1r, br1, att1, dl1, dr1, xl1, xr1, N, 128, 256, 4);
  k_gat1<<<GATB, TPB, 0, stream>>>(xl1, xr1, dl1, dr1, rowoff, csrc, att1, bias1, out1, N, NW);
  k_bnstat<<<128, TPB, 0, stream>>>(out1, N, part);
  k_bnfin<<<1, 64, 0, stream>>>(part, 128, N, g1, be1, ab1);

  // Layer 2
  k_prep2<<<(total4 + TPB - 1) / TPB, TPB, 0, stream>>>(out1, ab1, A2, total4);
  k_gemm_mfma<<<dim3(mtile, 1), TPB, 3 * 64 * 64 * 2, stream>>>(
      A2, wt2l, bl2, wt2r, br2, att2, dl2, dr2, xl2, xr2, N, 64, 64, 1);
  k_gat2<<<GATB, TPB, 0, stream>>>(xl2, xr2, dl2, dr2, rowoff, csrc, att2, bias2, out, N, NW);
  k_bnstat<<<128, TPB, 0, stream>>>(out, N, part);
  k_bnfin<<<1, 64, 0, stream>>>(part, 128, N, g2, be2, ab2);
  k_bnapply<<<(total4 + TPB - 1) / TPB, TPB, 0, stream>>>(out, ab2, out, total4);
}

// Round 4
// 389.795 us; speedup vs baseline: 1.7312x; 1.0393x over previous
//
#include <hip/hip_runtime.h>
#include <hip/hip_bf16.h>
#include <math.h>

#define TPB 256

typedef __attribute__((ext_vector_type(8))) short bfrag8;
typedef __attribute__((ext_vector_type(4))) float f32x4;
typedef __attribute__((ext_vector_type(2))) float f32x2;

static __device__ __forceinline__ float bf2f(unsigned int u) {
  union { unsigned int i; float f; } c; c.i = u << 16; return c.f;
}
// unpack a u32 holding two bf16 -> packed f32x2 {lo, hi}
static __device__ __forceinline__ f32x2 unpk2(unsigned int u) {
  union { unsigned int i; float f; } lo, hi;
  lo.i = u << 16;
  hi.i = u & 0xffff0000u;
  f32x2 r; r.x = lo.f; r.y = hi.f; return r;
}
static __device__ __forceinline__ unsigned short f2bf(float f) {
  union { float f; unsigned int i; } c; c.f = f;
  unsigned int lsb = (c.i >> 16) & 1u;
  return (unsigned short)((c.i + 0x7fffu + lsb) >> 16);
}

// ---------------- CSR build ----------------
__global__ void k_deg(const int* __restrict__ ei, int E, int ET, int* __restrict__ deg) {
  int e = blockIdx.x * blockDim.x + threadIdx.x;
  if (e >= ET) return;
  int dst = (e < E) ? ei[E + e] : (e - E);
  atomicAdd(&deg[dst], 1);
}

__global__ void k_scan1(const int* __restrict__ deg, int N, int* __restrict__ bsum) {
  __shared__ int sm[TPB];
  int i = blockIdx.x * TPB + threadIdx.x;
  sm[threadIdx.x] = (i < N) ? deg[i] : 0;
  __syncthreads();
  for (int d = TPB / 2; d > 0; d >>= 1) {
    if (threadIdx.x < d) sm[threadIdx.x] += sm[threadIdx.x + d];
    __syncthreads();
  }
  if (threadIdx.x == 0) bsum[blockIdx.x] = sm[0];
}

// requires SB <= TPB (N <= 65536)
__global__ void k_scan3(const int* __restrict__ deg, const int* __restrict__ bsum,
                        int SB, int N, int* __restrict__ rowoff, int* __restrict__ cursor) {
  __shared__ int sm[TPB];
  int pv = (threadIdx.x < blockIdx.x) ? bsum[threadIdx.x] : 0;
  sm[threadIdx.x] = pv;
  __syncthreads();
  for (int dd = TPB / 2; dd > 0; dd >>= 1) {
    if (threadIdx.x < dd) sm[threadIdx.x] += sm[threadIdx.x + dd];
    __syncthreads();
  }
  int base = sm[0];
  __syncthreads();
  int i = blockIdx.x * TPB + threadIdx.x;
  int v = (i < N) ? deg[i] : 0;
  sm[threadIdx.x] = v;
  __syncthreads();
  for (int dd = 1; dd < TPB; dd <<= 1) {
    int t = (threadIdx.x >= dd) ? sm[threadIdx.x - dd] : 0;
    __syncthreads();
    sm[threadIdx.x] += t;
    __syncthreads();
  }
  if (i < N) {
    int off = base + sm[threadIdx.x] - v;  // exclusive
    rowoff[i] = off;
    cursor[i] = off;
  }
  if (blockIdx.x == SB - 1 && threadIdx.x == TPB - 1) rowoff[N] = base + sm[TPB - 1];
}

__global__ void k_fill(const int* __restrict__ ei, int E, int ET,
                       int* __restrict__ cursor, int* __restrict__ csrc) {
  int e = blockIdx.x * blockDim.x + threadIdx.x;
  if (e >= ET) return;
  int src, dst;
  if (e < E) { src = ei[e]; dst = ei[E + e]; } else { src = dst = e - E; }
  int pos = atomicAdd(&cursor[dst], 1);
  csrc[pos] = src;
}

// ---------------- prep: f32 -> bf16 conversions (x, transposed W's) ----------------
__global__ void k_prep1(const float* __restrict__ x,
                        const float* __restrict__ Wl1, const float* __restrict__ Wr1,
                        const float* __restrict__ Wl2, const float* __restrict__ Wr2,
                        unsigned short* __restrict__ xb,
                        unsigned short* __restrict__ wt1l, unsigned short* __restrict__ wt1r,
                        unsigned short* __restrict__ wt2l, unsigned short* __restrict__ wt2r,
                        int nx4) {
  int i = blockIdx.x * blockDim.x + threadIdx.x;
  int stride = gridDim.x * blockDim.x;
  int wtot = nx4 + 65536 + 8192;
  for (; i < wtot; i += stride) {
    if (i < nx4) {
      float4 v = *(const float4*)(x + (size_t)i * 4);
      ushort4 o; o.x = f2bf(v.x); o.y = f2bf(v.y); o.z = f2bf(v.z); o.w = f2bf(v.w);
      *(ushort4*)(xb + (size_t)i * 4) = o;
    } else if (i < nx4 + 32768) {
      int j = i - nx4; int c = j >> 7, k = j & 127;
      wt1l[j] = f2bf(Wl1[(size_t)k * 256 + c]);
    } else if (i < nx4 + 65536) {
      int j = i - nx4 - 32768; int c = j >> 7, k = j & 127;
      wt1r[j] = f2bf(Wr1[(size_t)k * 256 + c]);
    } else if (i < nx4 + 65536 + 4096) {
      int j = i - nx4 - 65536; int c = j >> 6, k = j & 63;
      wt2l[j] = f2bf(Wl2[(size_t)k * 64 + c]);
    } else {
      int j = i - nx4 - 69632; int c = j >> 6, k = j & 63;
      wt2r[j] = f2bf(Wr2[(size_t)k * 64 + c]);
    }
  }
}

// prep2: BN affine + relu + bf16 (layer-2 GEMM input)
__global__ void k_prep2(const float* __restrict__ in, const float* __restrict__ ab,
                        unsigned short* __restrict__ o, int n4) {
  int i = blockIdx.x * blockDim.x + threadIdx.x;
  if (i >= n4) return;
  float4 v = *(const float4*)(in + (size_t)i * 4);
  int c0 = (i & 15) * 4;
  ushort4 u;
  u.x = f2bf(fmaxf(v.x * ab[c0 + 0] + ab[64 + c0 + 0], 0.f));
  u.y = f2bf(fmaxf(v.y * ab[c0 + 1] + ab[64 + c0 + 1], 0.f));
  u.z = f2bf(fmaxf(v.z * ab[c0 + 2] + ab[64 + c0 + 2], 0.f));
  u.w = f2bf(fmaxf(v.w * ab[c0 + 3] + ab[64 + c0 + 3], 0.f));
  *(ushort4*)(o + (size_t)i * 4) = u;
}

// ---------------- MFMA GEMM (bf16 in): out{0,1} = Ab @ Wt{0,1}^T + b{0,1} ----------------
// LDS XOR-swizzled (T2). Wt pre-transposed [Nc][K] bf16.
__global__ void k_gemm_mfma(const unsigned short* __restrict__ Ab,
                            const unsigned short* __restrict__ Wt0, const float* __restrict__ b0,
                            const unsigned short* __restrict__ Wt1, const float* __restrict__ b1,
                            unsigned short* __restrict__ out0, unsigned short* __restrict__ out1,
                            int M, int K, int Nc) {
  extern __shared__ short lds[];
  short* As = lds;
  short* Bls = lds + 64 * K;
  short* Brs = lds + 128 * K;
  const int r0 = blockIdx.x * 64, n0 = blockIdx.y * 64;
  const int tid = threadIdx.x;
  const int Kb = K * 2;
  const int cpr = K >> 3;          // 16B chunks per row
  const int chunks = 64 * cpr;
  for (int idx = tid; idx < chunks; idx += TPB) {
    int row = idx / cpr, k8 = (idx - row * cpr) * 8;
    int kb = (k8 * 2) ^ ((row & 7) << 4);
    int gr = r0 + row;
    uint4 av = make_uint4(0, 0, 0, 0);
    if (gr < M) av = *(const uint4*)(Ab + (size_t)gr * K + k8);
    *(uint4*)((char*)As + row * Kb + kb) = av;
    uint4 w0 = *(const uint4*)(Wt0 + (size_t)(n0 + row) * K + k8);
    *(uint4*)((char*)Bls + row * Kb + kb) = w0;
    uint4 w1 = *(const uint4*)(Wt1 + (size_t)(n0 + row) * K + k8);
    *(uint4*)((char*)Brs + row * Kb + kb) = w1;
  }
  __syncthreads();

  const int w = tid >> 6, lane = tid & 63;
  const int arow = w * 16 + (lane & 15);
  const int l16 = (lane >> 4) << 3;
  f32x4 accL[4], accR[4];
#pragma unroll
  for (int i = 0; i < 4; ++i) { accL[i] = (f32x4)0.f; accR[i] = (f32x4)0.f; }
  for (int k0 = 0; k0 < K; k0 += 32) {
    int kb = (k0 + l16) * 2;
    bfrag8 af = *(bfrag8*)((char*)As + arow * Kb + (kb ^ ((arow & 7) << 4)));
#pragma unroll
    for (int cf = 0; cf < 4; ++cf) {
      int col = cf * 16 + (lane & 15);
      int cb = col * Kb + (kb ^ ((col & 7) << 4));
      bfrag8 bl = *(bfrag8*)((char*)Bls + cb);
      accL[cf] = __builtin_amdgcn_mfma_f32_16x16x32_bf16(af, bl, accL[cf], 0, 0, 0);
      bfrag8 br = *(bfrag8*)((char*)Brs + cb);
      accR[cf] = __builtin_amdgcn_mfma_f32_16x16x32_bf16(af, br, accR[cf], 0, 0, 0);
    }
  }
  // epilogue: C/D map col=lane&15, row=(lane>>4)*4+reg
  const int rbase = r0 + w * 16 + ((lane >> 4) << 2);
  const int cbase = n0 + (lane & 15);
#pragma unroll
  for (int cf = 0; cf < 4; ++cf) {
    int gcol = cbase + cf * 16;
    float bb0 = b0[gcol], bb1 = b1[gcol];
#pragma unroll
    for (int r = 0; r < 4; ++r) {
      int grow = rbase + r;
      if (grow < M) {
        out0[(size_t)grow * Nc + gcol] = f2bf(accL[cf][r] + bb0);
        out1[(size_t)grow * Nc + gcol] = f2bf(accR[cf][r] + bb1);
      }
    }
  }
}

// ---------------- GATv2 layer 1: H=4, C=64; one node/wave; packed-f32 math ----------------
__global__ void k_gat1(const unsigned short* __restrict__ xl,
                       const unsigned short* __restrict__ xr,
                       const int* __restrict__ rowoff, const int* __restrict__ csrc,
                       const float* __restrict__ att, const float* __restrict__ bias,
                       float* __restrict__ out, int N) {
  int node = (blockIdx.x * blockDim.x + threadIdx.x) >> 6;
  int lane = threadIdx.x & 63;
  if (node >= N) return;
  int l4 = lane * 4;
  float4 atv = *(const float4*)(att + l4);
  f32x2 at01; at01.x = atv.x; at01.y = atv.y;
  f32x2 at23; at23.x = atv.z; at23.y = atv.w;
  float4 bb = *(const float4*)(bias + l4);
  uint2 rv = *(const uint2*)(xr + (size_t)node * 256 + l4);
  f32x2 xr01 = unpk2(rv.x), xr23 = unpk2(rv.y);
  int beg = rowoff[node], end = rowoff[node + 1];
  float s = 0.f;
  f32x2 ac01 = {0.f, 0.f}, ac23 = {0.f, 0.f};
  int k = beg;
  for (; k + 4 <= end; k += 4) {
    int srcs[4]; uint2 vv[4];
#pragma unroll
    for (int u = 0; u < 4; ++u) srcs[u] = csrc[k + u];
#pragma unroll
    for (int u = 0; u < 4; ++u) vv[u] = *(const uint2*)(xl + (size_t)srcs[u] * 256 + l4);
    f32x2 x01[4], x23[4]; float ps[4];
#pragma unroll
    for (int u = 0; u < 4; ++u) {
      x01[u] = unpk2(vv[u].x); x23[u] = unpk2(vv[u].y);
      f32x2 t01 = x01[u] + xr01, t23 = x23[u] + xr23;
      f32x2 m01 = t01 * 0.2f, m23 = t23 * 0.2f;
      f32x2 l01, l23;
      l01.x = fmaxf(t01.x, m01.x); l01.y = fmaxf(t01.y, m01.y);
      l23.x = fmaxf(t23.x, m23.x); l23.y = fmaxf(t23.y, m23.y);
      f32x2 pf = at01 * l01 + at23 * l23;
      ps[u] = pf.x + pf.y;
    }
#pragma unroll
    for (int u = 0; u < 4; ++u) {
      ps[u] += __shfl_xor(ps[u], 1); ps[u] += __shfl_xor(ps[u], 2);
      ps[u] += __shfl_xor(ps[u], 4); ps[u] += __shfl_xor(ps[u], 8);
    }
#pragma unroll
    for (int u = 0; u < 4; ++u) {
      float wv = __expf(ps[u]);
      s += wv;
      ac01 += x01[u] * wv;
      ac23 += x23[u] * wv;
    }
  }
  if (k < end) {  // predicated tail quad
    int srcs[4]; uint2 vv[4]; bool okv[4];
#pragma unroll
    for (int u = 0; u < 4; ++u) {
      okv[u] = (k + u) < end;
      srcs[u] = okv[u] ? csrc[k + u] : 0;
    }
#pragma unroll
    for (int u = 0; u < 4; ++u) vv[u] = *(const uint2*)(xl + (size_t)srcs[u] * 256 + l4);
    f32x2 x01[4], x23[4]; float ps[4];
#pragma unroll
    for (int u = 0; u < 4; ++u) {
      x01[u] = unpk2(vv[u].x); x23[u] = unpk2(vv[u].y);
      f32x2 t01 = x01[u] + xr01, t23 = x23[u] + xr23;
      f32x2 m01 = t01 * 0.2f, m23 = t23 * 0.2f;
      f32x2 l01, l23;
      l01.x = fmaxf(t01.x, m01.x); l01.y = fmaxf(t01.y, m01.y);
      l23.x = fmaxf(t23.x, m23.x); l23.y = fmaxf(t23.y, m23.y);
      f32x2 pf = at01 * l01 + at23 * l23;
      ps[u] = pf.x + pf.y;
    }
#pragma unroll
    for (int u = 0; u < 4; ++u) {
      ps[u] += __shfl_xor(ps[u], 1); ps[u] += __shfl_xor(ps[u], 2);
      ps[u] += __shfl_xor(ps[u], 4); ps[u] += __shfl_xor(ps[u], 8);
    }
#pragma unroll
    for (int u = 0; u < 4; ++u) {
      float wv = okv[u] ? __expf(ps[u]) : 0.f;
      s += wv;
      ac01 += x01[u] * wv;
      ac23 += x23[u] * wv;
    }
  }
  float inv = 1.f / (s + 1e-16f);
  float a0 = ac01.x * inv, a1 = ac01.y * inv, a2 = ac23.x * inv, a3 = ac23.y * inv;
  // mean over the 4 heads
  a0 += __shfl_xor(a0, 16); a0 += __shfl_xor(a0, 32);
  a1 += __shfl_xor(a1, 16); a1 += __shfl_xor(a1, 32);
  a2 += __shfl_xor(a2, 16); a2 += __shfl_xor(a2, 32);
  a3 += __shfl_xor(a3, 16); a3 += __shfl_xor(a3, 32);
  if (lane < 16) {
    float4 o;
    o.x = a0 * 0.25f + bb.x;
    o.y = a1 * 0.25f + bb.y;
    o.z = a2 * 0.25f + bb.z;
    o.w = a3 * 0.25f + bb.w;
    *(float4*)(out + (size_t)node * 64 + l4) = o;
  }
}

// ---------------- GATv2 layer 2: H=1, C=64; 4 edges/wave (16 lanes each) ----------------
__global__ void k_gat2(const unsigned short* __restrict__ xl,
                       const unsigned short* __restrict__ xr,
                       const int* __restrict__ rowoff, const int* __restrict__ csrc,
                       const float* __restrict__ att, const float* __restrict__ bias,
                       float* __restrict__ out, int N) {
  int node = (blockIdx.x * blockDim.x + threadIdx.x) >> 6;
  int lane = threadIdx.x & 63;
  if (node >= N) return;
  int grp = lane >> 4, c4 = (lane & 15) * 4;
  float4 atv = *(const float4*)(att + c4);
  f32x2 at01; at01.x = atv.x; at01.y = atv.y;
  f32x2 at23; at23.x = atv.z; at23.y = atv.w;
  float4 bb = *(const float4*)(bias + c4);
  uint2 rv = *(const uint2*)(xr + (size_t)node * 64 + c4);
  f32x2 xr01 = unpk2(rv.x), xr23 = unpk2(rv.y);
  int beg = rowoff[node], end = rowoff[node + 1];
  int iters = (end - beg + 3) >> 2;
  float s = 0.f;
  f32x2 ac01 = {0.f, 0.f}, ac23 = {0.f, 0.f};
  for (int it = 0; it < iters; ++it) {
    int kk = beg + it * 4 + grp;
    bool ok = kk < end;
    int src = ok ? csrc[kk] : 0;
    uint2 v = *(const uint2*)(xl + (size_t)src * 64 + c4);
    f32x2 x01 = unpk2(v.x), x23 = unpk2(v.y);
    f32x2 t01 = x01 + xr01, t23 = x23 + xr23;
    f32x2 m01 = t01 * 0.2f, m23 = t23 * 0.2f;
    f32x2 l01, l23;
    l01.x = fmaxf(t01.x, m01.x); l01.y = fmaxf(t01.y, m01.y);
    l23.x = fmaxf(t23.x, m23.x); l23.y = fmaxf(t23.y, m23.y);
    f32x2 pf = at01 * l01 + at23 * l23;
    float p = pf.x + pf.y;
    p += __shfl_xor(p, 1); p += __shfl_xor(p, 2);
    p += __shfl_xor(p, 4); p += __shfl_xor(p, 8);
    float wv = ok ? __expf(p) : 0.f;
    s += wv;
    ac01 += x01 * wv;
    ac23 += x23 * wv;
  }
  // sum the 4 edge-groups
  s += __shfl_xor(s, 16); s += __shfl_xor(s, 32);
  float a0 = ac01.x, a1 = ac01.y, a2 = ac23.x, a3 = ac23.y;
  a0 += __shfl_xor(a0, 16); a0 += __shfl_xor(a0, 32);
  a1 += __shfl_xor(a1, 16); a1 += __shfl_xor(a1, 32);
  a2 += __shfl_xor(a2, 16); a2 += __shfl_xor(a2, 32);
  a3 += __shfl_xor(a3, 16); a3 += __shfl_xor(a3, 32);
  if (lane < 16) {
    float inv = 1.f / (s + 1e-16f);
    float4 o;
    o.x = a0 * inv + bb.x;
    o.y = a1 * inv + bb.y;
    o.z = a2 * inv + bb.z;
    o.w = a3 * inv + bb.w;
    *(float4*)(out + (size_t)node * 64 + c4) = o;
  }
}

// ---------------- BatchNorm ----------------
__global__ void k_bnstat(const float* __restrict__ in, int N, float* __restrict__ part) {
  __shared__ float sm[TPB], sq[TPB];
  int col = threadIdx.x & 63;
  int rq = threadIdx.x >> 6;
  float s = 0.f, q = 0.f;
  for (int r = blockIdx.x * 4 + rq; r < N; r += gridDim.x * 4) {
    float v = in[(size_t)r * 64 + col];
    s += v; q += v * v;
  }
  sm[threadIdx.x] = s; sq[threadIdx.x] = q;
  __syncthreads();
  if (threadIdx.x < 64) {
    s = sm[threadIdx.x] + sm[threadIdx.x + 64] + sm[threadIdx.x + 128] + sm[threadIdx.x + 192];
    q = sq[threadIdx.x] + sq[threadIdx.x + 64] + sq[threadIdx.x + 128] + sq[threadIdx.x + 192];
    part[(size_t)blockIdx.x * 128 + threadIdx.x] = s;
    part[(size_t)blockIdx.x * 128 + 64 + threadIdx.x] = q;
  }
}

__global__ void k_bnfin(const float* __restrict__ part, int B, int N,
                        const float* __restrict__ g, const float* __restrict__ beta,
                        float* __restrict__ ab) {
  int c = threadIdx.x;  // 64 threads
  float s = 0.f, q = 0.f;
  for (int b = 0; b < B; ++b) {
    s += part[(size_t)b * 128 + c];
    q += part[(size_t)b * 128 + 64 + c];
  }
  float mean = s / (float)N;
  float var = q / (float)N - mean * mean;
  float a = g[c] * rsqrtf(var + 1e-5f);
  ab[c] = a;
  ab[64 + c] = beta[c] - mean * a;
}

__global__ void k_bnapply(const float* __restrict__ in, const float* __restrict__ ab,
                          float* __restrict__ out, int total4) {
  int idx = blockIdx.x * blockDim.x + threadIdx.x;
  if (idx >= total4) return;
  float4 v = *(const float4*)(in + (size_t)idx * 4);
  int c0 = (idx & 15) * 4;
  v.x = fmaxf(v.x * ab[c0 + 0] + ab[64 + c0 + 0], 0.f);
  v.y = fmaxf(v.y * ab[c0 + 1] + ab[64 + c0 + 1], 0.f);
  v.z = fmaxf(v.z * ab[c0 + 2] + ab[64 + c0 + 2], 0.f);
  v.w = fmaxf(v.w * ab[c0 + 3] + ab[64 + c0 + 3], 0.f);
  *(float4*)(out + (size_t)idx * 4) = v;
}

extern "C" void kernel_launch(void* const* d_in, const int* in_sizes, int n_in,
                              void* d_out, int out_size, void* d_ws, size_t ws_size,
                              hipStream_t stream) {
  const float* x     = (const float*)d_in[0];
  const int*   ei    = (const int*)d_in[1];
  const float* Wl1   = (const float*)d_in[2];
  const float* bl1   = (const float*)d_in[3];
  const float* Wr1   = (const float*)d_in[4];
  const float* br1   = (const float*)d_in[5];
  const float* att1  = (const float*)d_in[6];
  const float* bias1 = (const float*)d_in[7];
  const float* g1    = (const float*)d_in[8];
  const float* be1   = (const float*)d_in[9];
  const float* Wl2   = (const float*)d_in[10];
  const float* bl2   = (const float*)d_in[11];
  const float* Wr2   = (const float*)d_in[12];
  const float* br2   = (const float*)d_in[13];
  const float* att2  = (const float*)d_in[14];
  const float* bias2 = (const float*)d_in[15];
  const float* g2    = (const float*)d_in[16];
  const float* be2   = (const float*)d_in[17];
  float* out = (float*)d_out;

  const int N  = in_sizes[0] / 128;   // 50000
  const int E  = in_sizes[1] / 2;     // 800000
  const int ET = E + N;
  const int SB = (N + TPB - 1) / TPB; // 196 (<= TPB required)

  char* p = (char*)d_ws;
  auto take = [&](size_t b) { char* q = p; p += (b + 255) & ~(size_t)255; return q; };

  unsigned short* xl1 = (unsigned short*)take((size_t)N * 256 * 2);
  unsigned short* xr1 = (unsigned short*)take((size_t)N * 256 * 2);
  unsigned short* xl2 = (unsigned short*)take((size_t)N * 64 * 2);
  unsigned short* xr2 = (unsigned short*)take((size_t)N * 64 * 2);
  float* out1 = (float*)take((size_t)N * 64 * 4);
  unsigned short* xb = (unsigned short*)take((size_t)N * 128 * 2);  // reused as A2
  unsigned short* wt1l = (unsigned short*)take(256 * 128 * 2);
  unsigned short* wt1r = (unsigned short*)take(256 * 128 * 2);
  unsigned short* wt2l = (unsigned short*)take(64 * 64 * 2);
  unsigned short* wt2r = (unsigned short*)take(64 * 64 * 2);
  int* deg    = (int*)take((size_t)N * 4);
  int* rowoff = (int*)take((size_t)(N + 1) * 4);
  int* cursor = (int*)take((size_t)N * 4);
  int* csrc   = (int*)take((size_t)ET * 4);
  int* bsum   = (int*)take((size_t)SB * 4);
  float* part = (float*)take((size_t)128 * 128 * 4);
  float* ab1  = (float*)take(128 * 4);
  float* ab2  = (float*)take(128 * 4);
  (void)ws_size; (void)n_in; (void)out_size;

  unsigned short* A2 = xb;  // layer-2 GEMM input aliases xb (xb dead after gemm1)

  int egrid = (ET + TPB - 1) / TPB;
  int ngrid = (N + 3) / 4;            // one node per wave, 4 waves/block
  int mtile = (N + 63) / 64;          // 782
  int total4 = N * 16;
  int nx4 = N * 32;                   // N*128/4
  int wtot = nx4 + 65536 + 8192;

  // CSR build
  hipMemsetAsync(deg, 0, (size_t)N * 4, stream);
  k_deg<<<egrid, TPB, 0, stream>>>(ei, E, ET, deg);
  k_scan1<<<SB, TPB, 0, stream>>>(deg, N, bsum);
  k_scan3<<<SB, TPB, 0, stream>>>(deg, bsum, SB, N, rowoff, cursor);
  k_fill<<<egrid, TPB, 0, stream>>>(ei, E, ET, cursor, csrc);

  // prep: bf16 conversions
  k_prep1<<<(wtot + TPB - 1) / TPB, TPB, 0, stream>>>(x, Wl1, Wr1, Wl2, Wr2,
                                                      xb, wt1l, wt1r, wt2l, wt2r, nx4);

  // Layer 1
  k_gemm_mfma<<<dim3(mtile, 4), TPB, 3 * 64 * 128 * 2, stream>>>(
      xb, wt1l, bl1, wt1r, br1, xl1, xr1, N, 128, 256);
  k_gat1<<<ngrid, TPB, 0, stream>>>(xl1, xr1, rowoff, csrc, att1, bias1, out1, N);
  k_bnstat<<<128, TPB, 0, stream>>>(out1, N, part);
  k_bnfin<<<1, 64, 0, stream>>>(part, 128, N, g1, be1, ab1);

  // Layer 2
  k_prep2<<<(total4 + TPB - 1) / TPB, TPB, 0, stream>>>(out1, ab1, A2, total4);
  k_gemm_mfma<<<dim3(mtile, 1), TPB, 3 * 64 * 64 * 2, stream>>>(
      A2, wt2l, bl2, wt2r, br2, xl2, xr2, N, 64, 64);
  k_gat2<<<ngrid, TPB, 0, stream>>>(xl2, xr2, rowoff, csrc, att2, bias2, out, N);
  k_bnstat<<<128, TPB, 0, stream>>>(out, N, part);
  k_bnfin<<<1, 64, 0, stream>>>(part, 128, N, g2, be2, ab2);
  k_bnapply<<<(total4 + TPB - 1) / TPB, TPB, 0, stream>>>(out, ab2, out, total4);
}